// Round 1
// baseline (350.927 us; speedup 1.0000x reference)
//
#include <hip/hip_runtime.h>

typedef __bf16 bf16x8 __attribute__((ext_vector_type(8)));
typedef float floatx4 __attribute__((ext_vector_type(4)));
typedef unsigned short ushort8 __attribute__((ext_vector_type(8)));

__device__ __forceinline__ unsigned short f2bf(float f) {
    unsigned u = __float_as_uint(f);
    u += 0x7fffu + ((u >> 16) & 1u);   // round-to-nearest-even
    return (unsigned short)(u >> 16);
}

// ---------------------------------------------------------------------------
// Quantum gate helpers: one sample per thread, 64 complex amps in registers.
// ---------------------------------------------------------------------------
template <int ST>
__device__ __forceinline__ void apply_g(float* sr, float* si,
    float m00r, float m00i, float m01r, float m01i,
    float m10r, float m10i, float m11r, float m11i) {
#pragma unroll
    for (int i = 0; i < 64; ++i) {
        if ((i & ST) == 0) {
            int i1 = i + ST;
            float r0 = sr[i], u0 = si[i], r1 = sr[i1], u1 = si[i1];
            sr[i]  = m00r * r0 - m00i * u0 + m01r * r1 - m01i * u1;
            si[i]  = m00r * u0 + m00i * r0 + m01r * u1 + m01i * r1;
            sr[i1] = m10r * r0 - m10i * u0 + m11r * r1 - m11i * u1;
            si[i1] = m10r * u0 + m10i * r0 + m11r * u1 + m11i * r1;
        }
    }
}

template <int CB, int TB>
__device__ __forceinline__ void cnot_g(float* sr, float* si) {
#pragma unroll
    for (int i = 0; i < 64; ++i) {
        if ((i & CB) && !(i & TB)) {
            int i1 = i + TB;
            float tr = sr[i]; sr[i] = sr[i1]; sr[i1] = tr;
            float ti = si[i]; si[i] = si[i1]; si[i1] = ti;
        }
    }
}

// ---------------------------------------------------------------------------
// Fused front: prep (blocks 512..592) + enc + quantum + z->g (blocks 0..511).
// enc phase identical to the proven enc_kernel; angles never leave registers.
// Rot matrices are recomputed per block into LDS (18 threads of trig) so the
// umat global buffer and its producing dispatch disappear. Waves 1-3 exit
// after the enc reduce; wave 0 runs the circuit. Blocks at different phases
// interleave chip-wide, so the 512 circuit waves co-schedule with other
// blocks' enc waves instead of running on an empty GPU (old K2: 0.5 w/SIMD).
// ---------------------------------------------------------------------------
__global__ __launch_bounds__(256) void fused_front(
    const float* __restrict__ x, const float* __restrict__ w1,
    const float* __restrict__ b1, const float* __restrict__ w2,
    const float* __restrict__ b2, const float* __restrict__ qw,
    const float* __restrict__ hw1, const float* __restrict__ hb1,
    const float* __restrict__ hw2,
    unsigned short* __restrict__ w2t, unsigned short* __restrict__ g) {

    if (blockIdx.x >= 512) {
        // ---- prep: transpose head_w2 [128][1296] fp32 -> w2t [1296][128] bf16
        int t = (blockIdx.x - 512) * 256 + threadIdx.x;   // 81 blocks -> 20736
        int nn = t >> 4;
        int kc = (t & 15) * 8;
        if (nn < 1296) {
            ushort8 pk;
#pragma unroll
            for (int j = 0; j < 8; ++j) pk[j] = f2bf(hw2[(size_t)(kc + j) * 1296 + nn]);
            *(ushort8*)(w2t + (size_t)nn * 128 + kc) = pk;
        }
        return;   // no barriers executed by prep blocks
    }

    __shared__ float part[4][64][33];  // +1 pad: conflict-free
    __shared__ float hsh[64][33];
    __shared__ float umat_s[144];      // 18 Rot matrices * 8 floats

    // ---- phase 0: Rot matrices (covered by the enc-phase barrier below)
    if (threadIdx.x < 18) {
        int t = threadIdx.x;
        float phi = qw[t * 3], theta = qw[t * 3 + 1], omega = qw[t * 3 + 2];
        float c = cosf(0.5f * theta), s = sinf(0.5f * theta);
        float po = 0.5f * (phi + omega), pm = 0.5f * (phi - omega);
        float epr = cosf(po), epi = -sinf(po);
        float emr = cosf(pm), emi = -sinf(pm);
        float* u = umat_s + t * 8;
        u[0] = epr * c;  u[1] = epi * c;     // u00
        u[2] = -emr * s; u[3] = emi * s;     // u01 = -conj(em)*s
        u[4] = emr * s;  u[5] = emi * s;     // u10
        u[6] = epr * c;  u[7] = -epi * c;    // u11 = conj(ep)*c
    }

    // ---- phase 1: enc (identical to proven enc_kernel) ----------------------
    int lane = threadIdx.x & 63;
    int wave = threadIdx.x >> 6;
    int swave = __builtin_amdgcn_readfirstlane(wave);
    size_t row = (size_t)blockIdx.x * 64 + lane;
    const float2* x2 = (const float2*)(x + row * 512 + swave * 128);
    const float* wseg = w1 + swave * 128 * 32;  // wave-uniform -> scalar loads

    float acc[32];
#pragma unroll
    for (int j = 0; j < 32; ++j) acc[j] = 0.f;

#pragma clang loop unroll(disable)
    for (int k2 = 0; k2 < 64; ++k2) {
        float2 xv = x2[k2];
        const float* wr = wseg + k2 * 64;
#pragma unroll
        for (int j = 0; j < 32; ++j) acc[j] = fmaf(wr[j], xv.x, acc[j]);
#pragma unroll
        for (int j = 0; j < 32; ++j) acc[j] = fmaf(wr[32 + j], xv.y, acc[j]);
    }
#pragma unroll
    for (int j = 0; j < 32; ++j) part[wave][lane][j] = acc[j];
    __syncthreads();

    // reduce partials + bias + tanh
    int rl = threadIdx.x & 63;
    int jg = (threadIdx.x >> 6) * 8;
#pragma unroll
    for (int jj = 0; jj < 8; ++jj) {
        int j = jg + jj;
        float v = part[0][rl][j] + part[1][rl][j] + part[2][rl][j] + part[3][rl][j] + b1[j];
        hsh[rl][j] = tanhf(v);
    }
    __syncthreads();

    if (threadIdx.x >= 64) return;   // waves 1-3 done (no barriers below)

    // ---- phase 2: angles in registers (same arithmetic as the old
    //      store-to-global + load + *0.5f path: identical bits) -------------
    float h[32];
#pragma unroll
    for (int j = 0; j < 32; ++j) h[j] = hsh[threadIdx.x][j];
    float ca[6], sa[6];
#pragma unroll
    for (int q = 0; q < 6; ++q) {
        float a = b2[q];
#pragma unroll
        for (int j = 0; j < 32; ++j) a = fmaf(h[j], w2[j * 6 + q], a);
        a = 0.5f * a;
        ca[q] = cosf(a);
        sa[q] = sinf(a);
    }

    // ---- phase 3: circuit (identical to proven quantum_kernel) -------------
    float sr[64], si[64];
#pragma unroll
    for (int i = 0; i < 64; ++i) { sr[i] = 0.f; si[i] = 0.f; }
    sr[0] = 1.f;

#pragma clang loop unroll(disable)
    for (int layer = 0; layer < 3; ++layer) {
        const float* ub = umat_s + layer * 48;
#define DOQ(Q, ST) {                                                      \
        const float* u = ub + (Q) * 8;                                    \
        float c = ca[Q], ss = sa[Q];                                      \
        float m00r = u[0] * c + u[2] * ss, m00i = u[1] * c + u[3] * ss;   \
        float m01r = u[2] * c - u[0] * ss, m01i = u[3] * c - u[1] * ss;   \
        float m10r = u[4] * c + u[6] * ss, m10i = u[5] * c + u[7] * ss;   \
        float m11r = u[6] * c - u[4] * ss, m11i = u[7] * c - u[5] * ss;   \
        apply_g<ST>(sr, si, m00r, m00i, m01r, m01i, m10r, m10i, m11r, m11i); }
        DOQ(0, 32) DOQ(1, 16) DOQ(2, 8) DOQ(3, 4) DOQ(4, 2) DOQ(5, 1)
#undef DOQ
        cnot_g<32, 16>(sr, si);  // CNOT(0,1)
        cnot_g<8, 4>(sr, si);    // CNOT(2,3)
        cnot_g<2, 1>(sr, si);    // CNOT(4,5)
        cnot_g<16, 8>(sr, si);   // CNOT(1,2)
        cnot_g<4, 2>(sr, si);    // CNOT(3,4)
        cnot_g<1, 32>(sr, si);   // CNOT(5,0)
    }

    float z[6] = {0.f, 0.f, 0.f, 0.f, 0.f, 0.f};
#pragma unroll
    for (int i = 0; i < 64; ++i) {
        float p = sr[i] * sr[i] + si[i] * si[i];
        z[0] += (i & 32) ? -p : p;
        z[1] += (i & 16) ? -p : p;
        z[2] += (i & 8)  ? -p : p;
        z[3] += (i & 4)  ? -p : p;
        z[4] += (i & 2)  ? -p : p;
        z[5] += (i & 1)  ? -p : p;
    }

    // ---- phase 4: head layer 1 -> g (bf16) ---------------------------------
    int s = blockIdx.x * 64 + threadIdx.x;
    unsigned short* gp = g + (size_t)s * 128;
#pragma unroll 2
    for (int j0 = 0; j0 < 128; j0 += 8) {
        ushort8 pk;
#pragma unroll
        for (int jj = 0; jj < 8; ++jj) {
            int j = j0 + jj;
            float a = hb1[j];
#pragma unroll
            for (int q = 0; q < 6; ++q) a = fmaf(z[q], hw1[q * 128 + j], a);
            a = fmaxf(a, 0.f);
            pk[jj] = f2bf(a);
        }
        *(ushort8*)(gp + j0) = pk;
    }
}

// ---------------------------------------------------------------------------
// K3: head GEMM — out[32768][1296] = g@w2t^T + b2. (unchanged, proven)
// Wave tile: 48 cols (3 A-tiles) x 64 rows (4 B-subtiles) = 48 MFMA,
// 28 hoisted 16B loads, 12 float4 nontemporal stores. 13824 waves.
// ---------------------------------------------------------------------------
__global__ __launch_bounds__(256) void head_gemm(
    const unsigned short* __restrict__ g, const unsigned short* __restrict__ w2t,
    const float* __restrict__ b2, float* __restrict__ out) {
    int lane = threadIdx.x & 63;
    int task = blockIdx.x * 4 + (threadIdx.x >> 6);  // 13824 = 512 m * 27 n
    int m = task / 27;
    int n = task - m * 27;
    int row0 = m * 64, col0 = n * 48;
    int l15 = lane & 15, quad = lane >> 4;

    const unsigned short* ap = w2t + (size_t)(col0 + l15) * 128 + quad * 8;   // A: w2t
    const unsigned short* bp = g + (size_t)(row0 + l15) * 128 + quad * 8;     // B: g

    floatx4 acc[12];  // [t][sub]
#pragma unroll
    for (int i = 0; i < 12; ++i) acc[i] = (floatx4)0.f;

#pragma unroll
    for (int ks = 0; ks < 4; ++ks) {
        bf16x8 af[3], bf[4];
#pragma unroll
        for (int t = 0; t < 3; ++t) af[t] = *(const bf16x8*)(ap + (size_t)t * 16 * 128 + ks * 32);
#pragma unroll
        for (int sub = 0; sub < 4; ++sub) bf[sub] = *(const bf16x8*)(bp + (size_t)sub * 16 * 128 + ks * 32);
#pragma unroll
        for (int t = 0; t < 3; ++t)
#pragma unroll
            for (int sub = 0; sub < 4; ++sub)
                acc[t * 4 + sub] = __builtin_amdgcn_mfma_f32_16x16x32_bf16(af[t], bf[sub], acc[t * 4 + sub], 0, 0, 0);
    }

#pragma unroll
    for (int t = 0; t < 3; ++t) {
        const float* bb = b2 + col0 + t * 16 + quad * 4;
        floatx4 bias = { bb[0], bb[1], bb[2], bb[3] };
#pragma unroll
        for (int sub = 0; sub < 4; ++sub) {
            floatx4 v = acc[t * 4 + sub] + bias;
            floatx4* dst = (floatx4*)(out + (size_t)(row0 + sub * 16 + l15) * 1296 + col0 + t * 16 + quad * 4);
            __builtin_nontemporal_store(v, dst);
        }
    }
}

// ---------------------------------------------------------------------------
extern "C" void kernel_launch(void* const* d_in, const int* in_sizes, int n_in,
                              void* d_out, int out_size, void* d_ws, size_t ws_size,
                              hipStream_t stream) {
    const float* x   = (const float*)d_in[0];
    const float* ew1 = (const float*)d_in[1];
    const float* eb1 = (const float*)d_in[2];
    const float* ew2 = (const float*)d_in[3];
    const float* eb2 = (const float*)d_in[4];
    const float* qw  = (const float*)d_in[5];
    const float* hw1 = (const float*)d_in[6];
    const float* hb1 = (const float*)d_in[7];
    const float* hw2 = (const float*)d_in[8];
    const float* hb2 = (const float*)d_in[9];
    float* out = (float*)d_out;

    char* ws = (char*)d_ws;
    unsigned short* g   = (unsigned short*)(ws);             // 32768*128*2 = 8388608 B
    unsigned short* w2t = (unsigned short*)(ws + 8388608);   // 1296*128*2  = 331776 B

    fused_front<<<dim3(593), dim3(256), 0, stream>>>(x, ew1, eb1, ew2, eb2, qw, hw1, hb1, hw2, w2t, g);
    head_gemm<<<dim3(3456), dim3(256), 0, stream>>>(g, w2t, hb2, out);
}

// Round 2
// 342.853 us; speedup vs baseline: 1.0235x; 1.0235x over previous
//
#include <hip/hip_runtime.h>

typedef __bf16 bf16x8 __attribute__((ext_vector_type(8)));
typedef float floatx4 __attribute__((ext_vector_type(4)));
typedef unsigned short ushort8 __attribute__((ext_vector_type(8)));

__device__ __forceinline__ unsigned short f2bf(float f) {
    unsigned u = __float_as_uint(f);
    u += 0x7fffu + ((u >> 16) & 1u);   // round-to-nearest-even
    return (unsigned short)(u >> 16);
}

// ---------------------------------------------------------------------------
// Circuit helpers. State split 4-way: lane = p*16 + samp16, thread p holds
// global amplitudes i = p*16 + j (j in [0,16)). Qubit q <-> bit (32>>q):
// q0=bit32, q1=bit16 are cross-thread (shfl_xor 32/16); q2..q5 thread-local.
// Per-amplitude arithmetic identical to the proven register kernel.
// ---------------------------------------------------------------------------
template <int ST>   // ST in {8,4,2,1}: thread-local gate
__device__ __forceinline__ void apply_local(float* fr, float* fi,
    float m00r, float m00i, float m01r, float m01i,
    float m10r, float m10i, float m11r, float m11i) {
#pragma unroll
    for (int i = 0; i < 16; ++i) {
        if ((i & ST) == 0) {
            int i1 = i + ST;
            float r0 = fr[i], u0 = fi[i], r1 = fr[i1], u1 = fi[i1];
            fr[i]  = m00r * r0 - m00i * u0 + m01r * r1 - m01i * u1;
            fi[i]  = m00r * u0 + m00i * r0 + m01r * u1 + m01i * r1;
            fr[i1] = m10r * r0 - m10i * u0 + m11r * r1 - m11i * u1;
            fi[i1] = m10r * u0 + m10i * r0 + m11r * u1 + m11i * r1;
        }
    }
}

template <int XM>   // XM in {32,16}: cross-thread gate; hi = this thread is bit=1 side
__device__ __forceinline__ void apply_cross(float* fr, float* fi, bool hi,
    float m00r, float m00i, float m01r, float m01i,
    float m10r, float m10i, float m11r, float m11i) {
    float car = hi ? m10r : m00r, cai = hi ? m10i : m00i;
    float cbr = hi ? m11r : m01r, cbi = hi ? m11i : m01i;
#pragma unroll
    for (int j = 0; j < 16; ++j) {
        float mr = fr[j], mi = fi[j];
        float pr = __shfl_xor(mr, XM);
        float pi = __shfl_xor(mi, XM);
        float a0r = hi ? pr : mr, a0i = hi ? pi : mi;
        float a1r = hi ? mr : pr, a1i = hi ? mi : pi;
        fr[j] = car * a0r - cai * a0i + cbr * a1r - cbi * a1i;
        fi[j] = car * a0i + cai * a0r + cbr * a1i + cbi * a1r;
    }
}

#define SWAP2(a, b) { float _t = fr[a]; fr[a] = fr[b]; fr[b] = _t; \
                      _t = fi[a]; fi[a] = fi[b]; fi[b] = _t; }

// ---------------------------------------------------------------------------
// Fused front: prep (blocks 512..592) + enc + quantum + z->g (blocks 0..511).
// enc identical to the proven split-K kernel. Circuit phase: all 4 waves run,
// 16 samples/wave, 4 threads/sample -> 2048 circuit waves (8/CU, was 2/CU)
// and per-layer code ~9 KB (I-cache resident, was ~30 KB).
// ---------------------------------------------------------------------------
__global__ __launch_bounds__(256) void fused_front(
    const float* __restrict__ x, const float* __restrict__ w1,
    const float* __restrict__ b1, const float* __restrict__ w2,
    const float* __restrict__ b2, const float* __restrict__ qw,
    const float* __restrict__ hw1, const float* __restrict__ hb1,
    const float* __restrict__ hw2,
    unsigned short* __restrict__ w2t, unsigned short* __restrict__ g) {

    if (blockIdx.x >= 512) {
        // ---- prep: transpose head_w2 [128][1296] fp32 -> w2t [1296][128] bf16
        int t = (blockIdx.x - 512) * 256 + threadIdx.x;
        int nn = t >> 4;
        int kc = (t & 15) * 8;
        if (nn < 1296) {
            ushort8 pk;
#pragma unroll
            for (int j = 0; j < 8; ++j) pk[j] = f2bf(hw2[(size_t)(kc + j) * 1296 + nn]);
            *(ushort8*)(w2t + (size_t)nn * 128 + kc) = pk;
        }
        return;   // prep blocks execute no barriers
    }

    __shared__ float part[4][64][33];  // +1 pad: conflict-free
    __shared__ float hsh[64][33];
    __shared__ float umat_s[144];      // 18 Rot matrices * 8 floats
    __shared__ float casa[64][12];     // per-row cos/sin of half-angles

    // ---- phase 0: Rot matrices (covered by the enc barrier) ----------------
    if (threadIdx.x < 18) {
        int t = threadIdx.x;
        float phi = qw[t * 3], theta = qw[t * 3 + 1], omega = qw[t * 3 + 2];
        float c = cosf(0.5f * theta), s = sinf(0.5f * theta);
        float po = 0.5f * (phi + omega), pm = 0.5f * (phi - omega);
        float epr = cosf(po), epi = -sinf(po);
        float emr = cosf(pm), emi = -sinf(pm);
        float* u = umat_s + t * 8;
        u[0] = epr * c;  u[1] = epi * c;     // u00
        u[2] = -emr * s; u[3] = emi * s;     // u01 = -conj(em)*s
        u[4] = emr * s;  u[5] = emi * s;     // u10
        u[6] = epr * c;  u[7] = -epi * c;    // u11 = conj(ep)*c
    }

    // ---- phase 1: enc (identical to proven kernel) -------------------------
    int lane = threadIdx.x & 63;
    int wave = threadIdx.x >> 6;
    int swave = __builtin_amdgcn_readfirstlane(wave);
    size_t row = (size_t)blockIdx.x * 64 + lane;
    const float2* x2 = (const float2*)(x + row * 512 + swave * 128);
    const float* wseg = w1 + swave * 128 * 32;  // wave-uniform -> scalar loads

    float acc[32];
#pragma unroll
    for (int j = 0; j < 32; ++j) acc[j] = 0.f;

#pragma clang loop unroll(disable)
    for (int k2 = 0; k2 < 64; ++k2) {
        float2 xv = x2[k2];
        const float* wr = wseg + k2 * 64;
#pragma unroll
        for (int j = 0; j < 32; ++j) acc[j] = fmaf(wr[j], xv.x, acc[j]);
#pragma unroll
        for (int j = 0; j < 32; ++j) acc[j] = fmaf(wr[32 + j], xv.y, acc[j]);
    }
#pragma unroll
    for (int j = 0; j < 32; ++j) part[wave][lane][j] = acc[j];
    __syncthreads();

    // reduce partials + bias + tanh
    {
        int rl = threadIdx.x & 63;
        int jg = (threadIdx.x >> 6) * 8;
#pragma unroll
        for (int jj = 0; jj < 8; ++jj) {
            int j = jg + jj;
            float v = part[0][rl][j] + part[1][rl][j] + part[2][rl][j] + part[3][rl][j] + b1[j];
            hsh[rl][j] = tanhf(v);
        }
    }
    __syncthreads();

    // ---- phase 2: angles -> cos/sin in LDS (parallel over (row,q)) ---------
    {
        int row_a = threadIdx.x & 63;
        for (int qq = threadIdx.x >> 6; qq < 6; qq += 4) {
            float a = b2[qq];
#pragma unroll
            for (int j = 0; j < 32; ++j) a = fmaf(hsh[row_a][j], w2[j * 6 + qq], a);
            a *= 0.5f;
            casa[row_a][qq]     = cosf(a);
            casa[row_a][qq + 6] = sinf(a);
        }
    }
    __syncthreads();

    // ---- phase 3: circuit, 4 threads per sample ----------------------------
    int samp = wave * 16 + (lane & 15);
    int p = lane >> 4;
    bool podd = (p & 1) != 0;
    bool phi1 = (p >> 1) != 0;

    float ca[6], sa[6];
#pragma unroll
    for (int q = 0; q < 6; ++q) { ca[q] = casa[samp][q]; sa[q] = casa[samp][q + 6]; }

    float fr[16], fi[16];
#pragma unroll
    for (int j = 0; j < 16; ++j) { fr[j] = 0.f; fi[j] = 0.f; }
    fr[0] = (p == 0) ? 1.f : 0.f;

#pragma clang loop unroll(disable)
    for (int layer = 0; layer < 3; ++layer) {
        const float* ub = umat_s + layer * 48;
#define MAT(Q)                                                            \
        const float* u = ub + (Q) * 8;                                    \
        float c = ca[Q], ss = sa[Q];                                      \
        float m00r = u[0] * c + u[2] * ss, m00i = u[1] * c + u[3] * ss;   \
        float m01r = u[2] * c - u[0] * ss, m01i = u[3] * c - u[1] * ss;   \
        float m10r = u[4] * c + u[6] * ss, m10i = u[5] * c + u[7] * ss;   \
        float m11r = u[6] * c - u[4] * ss, m11i = u[7] * c - u[5] * ss;
        { MAT(0) apply_cross<32>(fr, fi, phi1, m00r, m00i, m01r, m01i, m10r, m10i, m11r, m11i); }
        { MAT(1) apply_cross<16>(fr, fi, podd, m00r, m00i, m01r, m01i, m10r, m10i, m11r, m11i); }
        { MAT(2) apply_local<8>(fr, fi, m00r, m00i, m01r, m01i, m10r, m10i, m11r, m11i); }
        { MAT(3) apply_local<4>(fr, fi, m00r, m00i, m01r, m01i, m10r, m10i, m11r, m11i); }
        { MAT(4) apply_local<2>(fr, fi, m00r, m00i, m01r, m01i, m10r, m10i, m11r, m11i); }
        { MAT(5) apply_local<1>(fr, fi, m00r, m00i, m01r, m01i, m10r, m10i, m11r, m11i); }
#undef MAT
        // CNOT(0,1): bit32 set -> flip bit16: p>=2 exchange with lane^16
#pragma unroll
        for (int j = 0; j < 16; ++j) {
            float pr = __shfl_xor(fr[j], 16);
            float pi = __shfl_xor(fi[j], 16);
            fr[j] = phi1 ? pr : fr[j];
            fi[j] = phi1 ? pi : fi[j];
        }
        // CNOT(2,3): j&8 -> flip bit4 (static renames)
        SWAP2(8, 12) SWAP2(9, 13) SWAP2(10, 14) SWAP2(11, 15)
        // CNOT(4,5): j&2 -> flip bit1
        SWAP2(2, 3) SWAP2(6, 7) SWAP2(10, 11) SWAP2(14, 15)
        // CNOT(1,2): bit16 set (p odd) -> flip bit8: j <-> j^8
        {
            float tr[16], ti[16];
#pragma unroll
            for (int j = 0; j < 16; ++j) { tr[j] = fr[j]; ti[j] = fi[j]; }
#pragma unroll
            for (int j = 0; j < 16; ++j) {
                fr[j] = podd ? tr[j ^ 8] : tr[j];
                fi[j] = podd ? ti[j ^ 8] : ti[j];
            }
        }
        // CNOT(3,4): j&4 -> flip bit2
        SWAP2(4, 6) SWAP2(5, 7) SWAP2(12, 14) SWAP2(13, 15)
        // CNOT(5,0): j odd -> flip bit32: exchange with lane^32
#pragma unroll
        for (int j = 1; j < 16; j += 2) {
            fr[j] = __shfl_xor(fr[j], 32);
            fi[j] = __shfl_xor(fi[j], 32);
        }
    }

    // ---- z expectations: per-thread partial, butterfly over the 4 parts ----
    float zt = 0.f, z2 = 0.f, z3 = 0.f, z4 = 0.f, z5 = 0.f;
#pragma unroll
    for (int j = 0; j < 16; ++j) {
        float pp = fr[j] * fr[j] + fi[j] * fi[j];
        zt += pp;
        z2 += (j & 8) ? -pp : pp;
        z3 += (j & 4) ? -pp : pp;
        z4 += (j & 2) ? -pp : pp;
        z5 += (j & 1) ? -pp : pp;
    }
    float zz[6];
    zz[0] = phi1 ? -zt : zt;
    zz[1] = podd ? -zt : zt;
    zz[2] = z2; zz[3] = z3; zz[4] = z4; zz[5] = z5;
#pragma unroll
    for (int q = 0; q < 6; ++q) {
        zz[q] += __shfl_xor(zz[q], 16);
        zz[q] += __shfl_xor(zz[q], 32);
    }

    // ---- head layer 1 -> g (bf16); each thread writes 32 of 128 outputs ----
    int s = blockIdx.x * 64 + samp;
    unsigned short* gp = g + (size_t)s * 128 + p * 32;
#pragma unroll
    for (int j0 = 0; j0 < 32; j0 += 8) {
        ushort8 pk;
#pragma unroll
        for (int jj = 0; jj < 8; ++jj) {
            int j = p * 32 + j0 + jj;
            float a = hb1[j];
#pragma unroll
            for (int q = 0; q < 6; ++q) a = fmaf(zz[q], hw1[q * 128 + j], a);
            a = fmaxf(a, 0.f);
            pk[jj] = f2bf(a);
        }
        *(ushort8*)(gp + j0) = pk;
    }
}

// ---------------------------------------------------------------------------
// K3: head GEMM — out[32768][1296] = g@w2t^T + b2. (unchanged, proven)
// ---------------------------------------------------------------------------
__global__ __launch_bounds__(256) void head_gemm(
    const unsigned short* __restrict__ g, const unsigned short* __restrict__ w2t,
    const float* __restrict__ b2, float* __restrict__ out) {
    int lane = threadIdx.x & 63;
    int task = blockIdx.x * 4 + (threadIdx.x >> 6);  // 13824 = 512 m * 27 n
    int m = task / 27;
    int n = task - m * 27;
    int row0 = m * 64, col0 = n * 48;
    int l15 = lane & 15, quad = lane >> 4;

    const unsigned short* ap = w2t + (size_t)(col0 + l15) * 128 + quad * 8;   // A: w2t
    const unsigned short* bp = g + (size_t)(row0 + l15) * 128 + quad * 8;     // B: g

    floatx4 acc[12];  // [t][sub]
#pragma unroll
    for (int i = 0; i < 12; ++i) acc[i] = (floatx4)0.f;

#pragma unroll
    for (int ks = 0; ks < 4; ++ks) {
        bf16x8 af[3], bf[4];
#pragma unroll
        for (int t = 0; t < 3; ++t) af[t] = *(const bf16x8*)(ap + (size_t)t * 16 * 128 + ks * 32);
#pragma unroll
        for (int sub = 0; sub < 4; ++sub) bf[sub] = *(const bf16x8*)(bp + (size_t)sub * 16 * 128 + ks * 32);
#pragma unroll
        for (int t = 0; t < 3; ++t)
#pragma unroll
            for (int sub = 0; sub < 4; ++sub)
                acc[t * 4 + sub] = __builtin_amdgcn_mfma_f32_16x16x32_bf16(af[t], bf[sub], acc[t * 4 + sub], 0, 0, 0);
    }

#pragma unroll
    for (int t = 0; t < 3; ++t) {
        const float* bb = b2 + col0 + t * 16 + quad * 4;
        floatx4 bias = { bb[0], bb[1], bb[2], bb[3] };
#pragma unroll
        for (int sub = 0; sub < 4; ++sub) {
            floatx4 v = acc[t * 4 + sub] + bias;
            floatx4* dst = (floatx4*)(out + (size_t)(row0 + sub * 16 + l15) * 1296 + col0 + t * 16 + quad * 4);
            __builtin_nontemporal_store(v, dst);
        }
    }
}

// ---------------------------------------------------------------------------
extern "C" void kernel_launch(void* const* d_in, const int* in_sizes, int n_in,
                              void* d_out, int out_size, void* d_ws, size_t ws_size,
                              hipStream_t stream) {
    const float* x   = (const float*)d_in[0];
    const float* ew1 = (const float*)d_in[1];
    const float* eb1 = (const float*)d_in[2];
    const float* ew2 = (const float*)d_in[3];
    const float* eb2 = (const float*)d_in[4];
    const float* qw  = (const float*)d_in[5];
    const float* hw1 = (const float*)d_in[6];
    const float* hb1 = (const float*)d_in[7];
    const float* hw2 = (const float*)d_in[8];
    const float* hb2 = (const float*)d_in[9];
    float* out = (float*)d_out;

    char* ws = (char*)d_ws;
    unsigned short* g   = (unsigned short*)(ws);             // 32768*128*2 = 8388608 B
    unsigned short* w2t = (unsigned short*)(ws + 8388608);   // 1296*128*2  = 331776 B

    fused_front<<<dim3(593), dim3(256), 0, stream>>>(x, ew1, eb1, ew2, eb2, qw, hw1, hb1, hw2, w2t, g);
    head_gemm<<<dim3(3456), dim3(256), 0, stream>>>(g, w2t, hb2, out);
}